// Round 9
// baseline (1699.820 us; speedup 1.0000x reference)
//
#include <hip/hip_runtime.h>
#include <math.h>

// SingleGAP: per-point tiny MLPs + GLOBAL softmax over N (axis 0, faithful bug),
// then attention-weighted sum. out0 = [N][16] x_attn, out1 = [N][160] h2 (flat,
// [F][K] order per point == x2v raw reshape).
//
// K1 (octet, sector-clean): 8 lanes/point, lane o owns f={2o,2o+1}.
//   - loads: own[i] = row[32i+4o..+3] -> each instr covers a full 128B line/pt.
//   - compute: 160 ds_swizzle 8-lane broadcasts (r = 32i+4src+e), local FMAs.
//   - out1: acc -> wave-private LDS (stride-80 ok in LDS) -> linear readback ->
//     contiguous 1KB/instr global stores. No barriers (in-order DS per wave).
//   - logits -> out0 (full sector), online (m,s) -> partials.
// K2: reduce per-block (m,s) -> global (m,s) per k-slot.
// K3: quad-per-point weighted sum: out0 = softmax(logits) @ x2v.

__device__ __forceinline__ void comb(float& m, float& s, float om, float os) {
  float M = fmaxf(m, om);
  if (M == -INFINITY) return;  // both empty
  s = s * __expf(m - M) + os * __expf(om - M);
  m = M;
}

// Broadcast lane (group_base + B) to all 8 lanes of its group (groups of 8).
// ds_swizzle BitMode: src_lane = (lane & 0x18) | B  (per 32-lane half).
template <int B>
__device__ __forceinline__ float swz8(float v) {
  return __int_as_float(
      __builtin_amdgcn_ds_swizzle(__float_as_int(v), (B << 5) | 0x18));
}

__device__ __forceinline__ float f4e(const float4& v, int e) {
  return (e == 0) ? v.x : (e == 1) ? v.y : (e == 2) ? v.z : v.w;
}

__global__ __launch_bounds__(256, 4) void gap_k1(
    const float* __restrict__ xknn, const float* __restrict__ x,
    const float* __restrict__ Wf, const float* __restrict__ bf,
    const float* __restrict__ W1, const float* __restrict__ b1p,
    float* __restrict__ out, float* __restrict__ partials, int n) {
  __shared__ float sx[4][8][164];   // wave-private redistribute scratch (pad 4)
  __shared__ float s_red[4][16][2];

  const int tid = threadIdx.x;
  const int o = tid & 7;        // octet lane: owns f = {2o,2o+1}
  const int p8 = tid >> 3;      // point-in-block 0..31
  const int pw = p8 & 7;        // point-in-wave 0..7
  const int lane = tid & 63;
  const int wave = tid >> 6;

  // per-lane weights: Wf rows {2o,2o+1}
  float wfo[2][16], w1o[2], bfo[2];
#pragma unroll
  for (int fp = 0; fp < 2; ++fp) {
    const float* wr = Wf + (size_t)(2 * o + fp) * 16;
#pragma unroll
    for (int dq = 0; dq < 4; ++dq) {
      float4 v = *(const float4*)(wr + dq * 4);
      wfo[fp][dq * 4 + 0] = v.x;
      wfo[fp][dq * 4 + 1] = v.y;
      wfo[fp][dq * 4 + 2] = v.z;
      wfo[fp][dq * 4 + 3] = v.w;
    }
    w1o[fp] = W1[2 * o + fp];
    bfo[fp] = bf[2 * o + fp];
  }
  const float b1v = b1p[0];

  // u[d] = sum_f W1[f] Wf[f][d]; keep only own pair u2 = {u[2o], u[2o+1]}
  float u2[2];
  {
    float ufull[16];
#pragma unroll
    for (int d = 0; d < 16; ++d)
      ufull[d] = fmaf(w1o[1], wfo[1][d], w1o[0] * wfo[0][d]);
#pragma unroll
    for (int mk = 1; mk < 8; mk <<= 1)
#pragma unroll
      for (int d = 0; d < 16; ++d) ufull[d] += __shfl_xor(ufull[d], mk);
#pragma unroll
    for (int j = 0; j < 2; ++j) {
      float v = ufull[j];
#pragma unroll
      for (int oo = 1; oo < 8; ++oo) v = (o == oo) ? ufull[2 * oo + j] : v;
      u2[j] = v;
    }
  }
  float sb = fmaf(w1o[1], bfo[1], w1o[0] * bfo[0]);
  sb += __shfl_xor(sb, 1);
  sb += __shfl_xor(sb, 2);
  sb += __shfl_xor(sb, 4);
  const float addA = sb + 2.0f * b1v;  // logit = t[k] + a1u + addA

  // online softmax state for owned k = {2o,2o+1} (valid for o<5)
  float rm[2] = {-INFINITY, -INFINITY}, rs[2] = {0.f, 0.f};

  float* out0 = out;                       // [n][16]  (logits now, x_attn later)
  float* out1 = out + (size_t)n * 16;      // [n][160] h2 flat ([F][K] per point)

  const long ntiles = ((long)n + 31) / 32;

  for (long t = (long)blockIdx.x; t < ntiles; t += gridDim.x) {
    const long pt = t * 32 + p8;
    const bool valid = (pt < n);

    // sector-major loads: instr i covers row bytes [128i,128i+128) per point
    const float* row = xknn + (valid ? (size_t)pt * 160 : (size_t)0);
    float4 own[5];
#pragma unroll
    for (int i = 0; i < 5; ++i)
      own[i] = *(const float4*)(row + 32 * i + 4 * o);
    const float2 xc =
        *(const float2*)(x + (valid ? (size_t)pt * 16 : (size_t)0) + 2 * o);

    // acc[fp][k] = bf + sum_d Wf[fp][d] x2[d][k]; element r = 32i + 4*src + e
    float acc0[10], acc1[10];
#pragma unroll
    for (int k = 0; k < 10; ++k) {
      acc0[k] = bfo[0];
      acc1[k] = bfo[1];
    }
#pragma unroll
    for (int i = 0; i < 5; ++i) {
#pragma unroll
      for (int e = 0; e < 4; ++e) {
        const float mine = f4e(own[i], e);
        {
          const int r = 32 * i + 0 + e, d = r / 10, k = r % 10;
          const float xv = swz8<0>(mine);
          acc0[k] = fmaf(wfo[0][d], xv, acc0[k]);
          acc1[k] = fmaf(wfo[1][d], xv, acc1[k]);
        }
        {
          const int r = 32 * i + 4 + e, d = r / 10, k = r % 10;
          const float xv = swz8<1>(mine);
          acc0[k] = fmaf(wfo[0][d], xv, acc0[k]);
          acc1[k] = fmaf(wfo[1][d], xv, acc1[k]);
        }
        {
          const int r = 32 * i + 8 + e, d = r / 10, k = r % 10;
          const float xv = swz8<2>(mine);
          acc0[k] = fmaf(wfo[0][d], xv, acc0[k]);
          acc1[k] = fmaf(wfo[1][d], xv, acc1[k]);
        }
        {
          const int r = 32 * i + 12 + e, d = r / 10, k = r % 10;
          const float xv = swz8<3>(mine);
          acc0[k] = fmaf(wfo[0][d], xv, acc0[k]);
          acc1[k] = fmaf(wfo[1][d], xv, acc1[k]);
        }
        {
          const int r = 32 * i + 16 + e, d = r / 10, k = r % 10;
          const float xv = swz8<4>(mine);
          acc0[k] = fmaf(wfo[0][d], xv, acc0[k]);
          acc1[k] = fmaf(wfo[1][d], xv, acc1[k]);
        }
        {
          const int r = 32 * i + 20 + e, d = r / 10, k = r % 10;
          const float xv = swz8<5>(mine);
          acc0[k] = fmaf(wfo[0][d], xv, acc0[k]);
          acc1[k] = fmaf(wfo[1][d], xv, acc1[k]);
        }
        {
          const int r = 32 * i + 24 + e, d = r / 10, k = r % 10;
          const float xv = swz8<6>(mine);
          acc0[k] = fmaf(wfo[0][d], xv, acc0[k]);
          acc1[k] = fmaf(wfo[1][d], xv, acc1[k]);
        }
        {
          const int r = 32 * i + 28 + e, d = r / 10, k = r % 10;
          const float xv = swz8<7>(mine);
          acc0[k] = fmaf(wfo[0][d], xv, acc0[k]);
          acc1[k] = fmaf(wfo[1][d], xv, acc1[k]);
        }
      }
    }

    // a2[k]+sb via 3-step octet butterfly
    float tk[10];
#pragma unroll
    for (int k = 0; k < 10; ++k)
      tk[k] = fmaf(w1o[1], acc1[k], w1o[0] * acc0[k]);
#pragma unroll
    for (int k = 0; k < 10; ++k) tk[k] += __shfl_xor(tk[k], 1);
#pragma unroll
    for (int k = 0; k < 10; ++k) tk[k] += __shfl_xor(tk[k], 2);
#pragma unroll
    for (int k = 0; k < 10; ++k) tk[k] += __shfl_xor(tk[k], 4);

    // a1u = sum_d u[d] x[d] (octet butterfly)
    float a1u = fmaf(u2[1], xc.y, u2[0] * xc.x);
    a1u += __shfl_xor(a1u, 1);
    a1u += __shfl_xor(a1u, 2);
    a1u += __shfl_xor(a1u, 4);
    const float addc = a1u + addA;

    // logits k = {2o, 2o+1} (cndmask chains)
    float lj0 = 0.f, lj1 = 0.f;
#pragma unroll
    for (int kk = 0; kk < 10; ++kk) {
      lj0 = (kk == 2 * o) ? (tk[kk] + addc) : lj0;
      lj1 = (kk == 2 * o + 1) ? (tk[kk] + addc) : lj1;
    }

    if (valid) {
      *(float2*)(out0 + (size_t)pt * 16 + 2 * o) = make_float2(lj0, lj1);
      if (o < 5) {
        comb(rm[0], rs[0], lj0, 1.0f);
        comb(rm[1], rs[1], lj1, 1.0f);
      }
    }

    // out1 via wave-private LDS redistribute (no barrier needed):
    // write own f-major quarter [20o,20o+20), read back linearly, store 1KB/instr
    {
      float* lw = &sx[wave][pw][20 * o];
      *(float4*)(lw + 0) = make_float4(acc0[0], acc0[1], acc0[2], acc0[3]);
      *(float4*)(lw + 4) = make_float4(acc0[4], acc0[5], acc0[6], acc0[7]);
      *(float4*)(lw + 8) = make_float4(acc0[8], acc0[9], acc1[0], acc1[1]);
      *(float4*)(lw + 12) = make_float4(acc1[2], acc1[3], acc1[4], acc1[5]);
      *(float4*)(lw + 16) = make_float4(acc1[6], acc1[7], acc1[8], acc1[9]);
    }
    __builtin_amdgcn_wave_barrier();   // pin compiler order (HW DS is in-order)
    {
      const long wbase = t * 32 + wave * 8;
#pragma unroll
      for (int c = 0; c < 5; ++c) {
        const int idx = 64 * c + lane;      // float4 index 0..319 in wave tile
        const int pwr = idx / 40;           // point 0..7
        const int wo = idx - 40 * pwr;      // float4 within point 0..39
        const float4 v = *(const float4*)(&sx[wave][pwr][4 * wo]);
        const long gpt = wbase + pwr;
        if (gpt < n)
          *(float4*)(out1 + (size_t)gpt * 160 + 4 * wo) = v;
      }
    }
    __builtin_amdgcn_wave_barrier();   // next iter's ds_write after our reads
  }

  // (m,s) reduce across the wave's 8 points (lane bits 3..5), then block
#pragma unroll
  for (int mk = 8; mk < 64; mk <<= 1) {
#pragma unroll
    for (int j = 0; j < 2; ++j) {
      float om = __shfl_xor(rm[j], mk);
      float os = __shfl_xor(rs[j], mk);
      comb(rm[j], rs[j], om, os);
    }
  }
  if (lane < 5) {
#pragma unroll
    for (int j = 0; j < 2; ++j) {
      s_red[wave][2 * lane + j][0] = rm[j];
      s_red[wave][2 * lane + j][1] = rs[j];
    }
  }
  __syncthreads();
  if (tid < 10) {
    float m = s_red[0][tid][0], s = s_red[0][tid][1];
    comb(m, s, s_red[1][tid][0], s_red[1][tid][1]);
    comb(m, s, s_red[2][tid][0], s_red[2][tid][1]);
    comb(m, s, s_red[3][tid][0], s_red[3][tid][1]);
    partials[(size_t)blockIdx.x * 20 + tid * 2 + 0] = m;
    partials[(size_t)blockIdx.x * 20 + tid * 2 + 1] = s;
  }
}

__global__ __launch_bounds__(256) void gap_k2(const float* __restrict__ part,
                                              int nb, float* __restrict__ fin) {
  const int k = blockIdx.x;   // one block per k-slot
  const int tid = threadIdx.x;
  float m = -INFINITY, s = 0.f;
  for (int i = tid; i < nb; i += 256)
    comb(m, s, part[(size_t)i * 20 + k * 2], part[(size_t)i * 20 + k * 2 + 1]);
#pragma unroll
  for (int mask = 1; mask < 64; mask <<= 1) {
    float om = __shfl_xor(m, mask, 64);
    float os = __shfl_xor(s, mask, 64);
    comb(m, s, om, os);
  }
  __shared__ float sm[4][2];
  const int wave = tid >> 6, lane = tid & 63;
  if (lane == 0) { sm[wave][0] = m; sm[wave][1] = s; }
  __syncthreads();
  if (tid == 0) {
    for (int w = 1; w < 4; ++w) comb(m, s, sm[w][0], sm[w][1]);
    fin[k * 2 + 0] = m;
    fin[k * 2 + 1] = s;
  }
}

// K3: 4 lanes per point; lane (p,q) accumulates features f = 4q..4q+3.
// Reads out1 flat at offset k*16+f == x2v[k][f] (raw-reshape identity).
__global__ __launch_bounds__(256) void gap_k3(const float* __restrict__ fin,
                                              float* __restrict__ out, int n) {
  __shared__ float s_fin[20];
  if (threadIdx.x < 20) s_fin[threadIdx.x] = fin[threadIdx.x];
  __syncthreads();
  float mk[10], rsk[10];
#pragma unroll
  for (int k = 0; k < 10; ++k) {
    mk[k] = s_fin[2 * k];
    rsk[k] = 1.0f / s_fin[2 * k + 1];
  }
  float* out0 = out;
  const float* out1 = out + (size_t)n * 16;
  const int q = threadIdx.x & 3;
  const int pl = threadIdx.x >> 2;           // 64 points per block pass
  for (long i = (long)blockIdx.x * 64 + pl; i < n; i += (long)gridDim.x * 64) {
    float* lrow = out0 + i * 16;
    // all 4 lanes of the quad read the same 64B logit line (L1 broadcast)
    float4 la = *(const float4*)(lrow);
    float4 lb = *(const float4*)(lrow + 4);
    float2 lc = *(const float2*)(lrow + 8);
    float l[10] = {la.x, la.y, la.z, la.w, lb.x, lb.y, lb.z, lb.w, lc.x, lc.y};
    float w[10];
#pragma unroll
    for (int k = 0; k < 10; ++k) w[k] = __expf(l[k] - mk[k]) * rsk[k];
    const float* vrow = out1 + i * 160 + q * 4;
    float4 acc = make_float4(0.f, 0.f, 0.f, 0.f);
#pragma unroll
    for (int k = 0; k < 10; ++k) {
      float4 v = *(const float4*)(vrow + k * 16);
      float wk = w[k];
      acc.x = fmaf(wk, v.x, acc.x);
      acc.y = fmaf(wk, v.y, acc.y);
      acc.z = fmaf(wk, v.z, acc.z);
      acc.w = fmaf(wk, v.w, acc.w);
    }
    // store after all reads (wave-lockstep => no RAW hazard on the logit line)
    *(float4*)(lrow + q * 4) = acc;
  }
}

extern "C" void kernel_launch(void* const* d_in, const int* in_sizes, int n_in,
                              void* d_out, int out_size, void* d_ws, size_t ws_size,
                              hipStream_t stream) {
  const float* xknn = (const float*)d_in[0];
  const float* x    = (const float*)d_in[1];
  const float* Wf   = (const float*)d_in[2];
  const float* bf   = (const float*)d_in[3];
  const float* W1   = (const float*)d_in[4];
  const float* b1   = (const float*)d_in[5];
  float* out = (float*)d_out;
  const int n = in_sizes[1] / 16;  // x is [N][16]

  const int G1 = 2048;
  float* partials = (float*)d_ws;                 // [G1][10][2]
  float* finals = partials + (size_t)G1 * 20;     // [10][2]

  gap_k1<<<G1, 256, 0, stream>>>(xknn, x, Wf, bf, W1, b1, out, partials, n);
  gap_k2<<<10, 256, 0, stream>>>(partials, G1, finals);
  gap_k3<<<2048, 256, 0, stream>>>(finals, out, n);
}

// Round 10
// 925.361 us; speedup vs baseline: 1.8369x; 1.8369x over previous
//
#include <hip/hip_runtime.h>
#include <math.h>

// SingleGAP: per-point tiny MLPs + GLOBAL softmax over N (axis 0, faithful bug),
// then attention-weighted sum. out0 = [N][16] x_attn, out1 = [N][160] h2 (flat,
// [F][K] order per point == x2v raw reshape).
//
// K1 (R5 structure, Wf in LDS): quad-per-point. Lane q loads its contiguous
//     quarter [40q,40q+40) (proven-clean pattern), owns f=4q..4q+3. Weights come
//     from LDS WfT via one ds_read_b128 per d (quad covers the row; same-addr
//     broadcast). x2 values cross the quad via quad_perm DPP (VALU, no DS cost).
//     ~128 VGPR -> 4 waves/SIMD (vs R5's 156 -> 2).
// K2: reduce per-block (m,s) -> global (m,s) per k-slot.
// K3: quad-per-point weighted sum: out0 = softmax(logits) @ x2v.

__device__ __forceinline__ void comb(float& m, float& s, float om, float os) {
  float M = fmaxf(m, om);
  if (M == -INFINITY) return;  // both empty
  s = s * __expf(m - M) + os * __expf(om - M);
  m = M;
}

// Broadcast the value of quad-lane SRC to all 4 lanes of each quad (DPP, VALU).
template <int CTRL>
__device__ __forceinline__ float qb(float v) {
  return __int_as_float(__builtin_amdgcn_update_dpp(
      0, __float_as_int(v), CTRL, 0xf, 0xf, true));
}

__device__ __forceinline__ float f4e(const float4& v, int e) {
  // e is always a compile-time constant under full unroll
  return (e == 0) ? v.x : (e == 1) ? v.y : (e == 2) ? v.z : v.w;
}

__global__ __launch_bounds__(256, 2) void gap_k1(
    const float* __restrict__ xknn, const float* __restrict__ x,
    const float* __restrict__ Wf, const float* __restrict__ bf,
    const float* __restrict__ W1, const float* __restrict__ b1p,
    float* __restrict__ out, float* __restrict__ partials, int n) {
  __shared__ float s_wfT[16][16];   // WfT[d][f] = Wf[f][d]
  __shared__ float s_w1[16];
  __shared__ float s_red[4][16][2];

  const int tid = threadIdx.x;
  const int q = tid & 3;          // quad lane: owns f = 4q..4q+3, d = 4q..4q+3
  const int lane = tid & 63;
  const int wave = tid >> 6;

  // stage transposed Wf + W1 into LDS (once)
  {
    const int f = tid & 15, d = tid >> 4;
    if (tid < 256) s_wfT[d][f] = Wf[f * 16 + d];
    if (tid < 16) s_w1[tid] = W1[tid];
  }
  __syncthreads();

  // u4[dd] = u[4q+dd] = sum_f W1[f] Wf[f][4q+dd]
  float u4[4];
#pragma unroll
  for (int dd = 0; dd < 4; ++dd) {
    float t = 0.f;
#pragma unroll
    for (int f = 0; f < 16; ++f) t = fmaf(s_w1[f], s_wfT[4 * q + dd][f], t);
    u4[dd] = t;
  }
  // sb = sum_f W1[f] bf[f]  (redundant per thread, prologue-only)
  float sb = 0.f;
#pragma unroll
  for (int f = 0; f < 16; ++f) sb = fmaf(s_w1[f], bf[f], sb);
  const float addA = sb + 2.0f * b1p[0];  // logit = pa[k] + a1u + sb + 2*b1... (pa,a1u exclude sb)
  const float4 bfq = *(const float4*)(bf + 4 * q);

  // online softmax state for owned k = 4q+j (invalid slots stay empty)
  float rm[4] = {-INFINITY, -INFINITY, -INFINITY, -INFINITY};
  float rs[4] = {0.f, 0.f, 0.f, 0.f};

  float* out0 = out;                       // [n][16]  (logits now, x_attn later)
  float* out1 = out + (size_t)n * 16;      // [n][160] h2 flat ([F][K] per point)

  const long pt0 = (long)blockIdx.x * 64 + (tid >> 2);
  const long pstride = (long)gridDim.x * 64;

  for (long pt = pt0; pt < n; pt += pstride) {
    // own quarter: contiguous 160B per lane (proven-clean pattern)
    const float* rowq = xknn + (size_t)pt * 160 + 40 * q;
    float4 own[10];
#pragma unroll
    for (int j = 0; j < 10; ++j) own[j] = *(const float4*)(rowq + 4 * j);
    const float4 xc4 = *(const float4*)(x + (size_t)pt * 16 + 4 * q);

    // pa[k] partial over own d-quarter, then quad butterfly
    float pa[10];
#pragma unroll
    for (int k = 0; k < 10; ++k) pa[k] = 0.f;
#pragma unroll
    for (int rr = 0; rr < 40; ++rr) {
      const int dl = rr / 10, k = rr - dl * 10;
      pa[k] = fmaf(u4[dl], f4e(own[rr >> 2], rr & 3), pa[k]);
    }
#pragma unroll
    for (int k = 0; k < 10; ++k) pa[k] += __shfl_xor(pa[k], 1);
#pragma unroll
    for (int k = 0; k < 10; ++k) pa[k] += __shfl_xor(pa[k], 2);
    float a1u = u4[0] * xc4.x;
    a1u = fmaf(u4[1], xc4.y, a1u);
    a1u = fmaf(u4[2], xc4.z, a1u);
    a1u = fmaf(u4[3], xc4.w, a1u);
    a1u += __shfl_xor(a1u, 1);
    a1u += __shfl_xor(a1u, 2);
    const float addc = a1u + addA;

    // h2: acc[fp][k] = bf[4q+fp] + sum_d Wf[4q+fp][d] x2[d][k]
    // weights via ds_read_b128 from WfT[d][4q..4q+4); x2 via DPP from owner d>>2
    float acc0[10], acc1[10], acc2[10], acc3[10];
#pragma unroll
    for (int k = 0; k < 10; ++k) {
      acc0[k] = bfq.x;
      acc1[k] = bfq.y;
      acc2[k] = bfq.z;
      acc3[k] = bfq.w;
    }
#pragma unroll
    for (int d = 0; d < 16; ++d) {
      const float4 wfv = *(const float4*)(&s_wfT[d][4 * q]);
      const int dd = d & 3;
#pragma unroll
      for (int j = 0; j < 10; ++j) {
        const int e = 10 * dd + j;  // owner's local element index (compile-time)
        const float mine = f4e(own[e >> 2], e & 3);
        const float xv = ((d >> 2) == 0)   ? qb<0x00>(mine)
                         : ((d >> 2) == 1) ? qb<0x55>(mine)
                         : ((d >> 2) == 2) ? qb<0xAA>(mine)
                                           : qb<0xFF>(mine);
        acc0[j] = fmaf(wfv.x, xv, acc0[j]);
        acc1[j] = fmaf(wfv.y, xv, acc1[j]);
        acc2[j] = fmaf(wfv.z, xv, acc2[j]);
        acc3[j] = fmaf(wfv.w, xv, acc3[j]);
      }
    }

    // logits: lane q takes k = 4q..4q+3 (cndmask chain; no runtime array index)
    float lj[4];
#pragma unroll
    for (int j = 0; j < 4; ++j) {
      const int k = 4 * q + j;  // runtime q
      float v = 0.f;
#pragma unroll
      for (int kk = 0; kk < 10; ++kk) v = (kk == k) ? (pa[kk] + addc) : v;
      lj[j] = v;
      if (k < 10) comb(rm[j], rs[j], v, 1.0f);
    }
    *(float4*)(out0 + (size_t)pt * 16 + 4 * q) =
        make_float4(lj[0], lj[1], lj[2], lj[3]);

    // h2 -> out1 flat [F][K]: lane q's region [40q,40q+40), contiguous 160B
    float* o1 = out1 + (size_t)pt * 160 + 40 * q;
    *(float4*)(o1 + 0) = make_float4(acc0[0], acc0[1], acc0[2], acc0[3]);
    *(float4*)(o1 + 4) = make_float4(acc0[4], acc0[5], acc0[6], acc0[7]);
    *(float4*)(o1 + 8) = make_float4(acc0[8], acc0[9], acc1[0], acc1[1]);
    *(float4*)(o1 + 12) = make_float4(acc1[2], acc1[3], acc1[4], acc1[5]);
    *(float4*)(o1 + 16) = make_float4(acc1[6], acc1[7], acc1[8], acc1[9]);
    *(float4*)(o1 + 20) = make_float4(acc2[0], acc2[1], acc2[2], acc2[3]);
    *(float4*)(o1 + 24) = make_float4(acc2[4], acc2[5], acc2[6], acc2[7]);
    *(float4*)(o1 + 28) = make_float4(acc2[8], acc2[9], acc3[0], acc3[1]);
    *(float4*)(o1 + 32) = make_float4(acc3[2], acc3[3], acc3[4], acc3[5]);
    *(float4*)(o1 + 36) = make_float4(acc3[6], acc3[7], acc3[8], acc3[9]);
  }

  // reduce (m,s) across the wave's 16 quads (lanes differing in bits 2..5)
#pragma unroll
  for (int mask = 4; mask < 64; mask <<= 1) {
#pragma unroll
    for (int j = 0; j < 4; ++j) {
      float om = __shfl_xor(rm[j], mask);
      float os = __shfl_xor(rs[j], mask);
      comb(rm[j], rs[j], om, os);
    }
  }
  if (lane < 4) {  // lane == q-class representative; slot index = k = 4*lane+j
#pragma unroll
    for (int j = 0; j < 4; ++j) {
      s_red[wave][lane * 4 + j][0] = rm[j];
      s_red[wave][lane * 4 + j][1] = rs[j];
    }
  }
  __syncthreads();
  if (tid < 10) {
    float m = s_red[0][tid][0], s = s_red[0][tid][1];
    comb(m, s, s_red[1][tid][0], s_red[1][tid][1]);
    comb(m, s, s_red[2][tid][0], s_red[2][tid][1]);
    comb(m, s, s_red[3][tid][0], s_red[3][tid][1]);
    partials[(size_t)blockIdx.x * 20 + tid * 2 + 0] = m;
    partials[(size_t)blockIdx.x * 20 + tid * 2 + 1] = s;
  }
}

__global__ __launch_bounds__(256) void gap_k2(const float* __restrict__ part,
                                              int nb, float* __restrict__ fin) {
  const int k = blockIdx.x;   // one block per k-slot
  const int tid = threadIdx.x;
  float m = -INFINITY, s = 0.f;
  for (int i = tid; i < nb; i += 256)
    comb(m, s, part[(size_t)i * 20 + k * 2], part[(size_t)i * 20 + k * 2 + 1]);
#pragma unroll
  for (int mask = 1; mask < 64; mask <<= 1) {
    float om = __shfl_xor(m, mask, 64);
    float os = __shfl_xor(s, mask, 64);
    comb(m, s, om, os);
  }
  __shared__ float sm[4][2];
  const int wave = tid >> 6, lane = tid & 63;
  if (lane == 0) { sm[wave][0] = m; sm[wave][1] = s; }
  __syncthreads();
  if (tid == 0) {
    for (int w = 1; w < 4; ++w) comb(m, s, sm[w][0], sm[w][1]);
    fin[k * 2 + 0] = m;
    fin[k * 2 + 1] = s;
  }
}

// K3: 4 lanes per point; lane (p,q) accumulates features f = 4q..4q+3.
// Reads out1 flat at offset k*16+f == x2v[k][f] (raw-reshape identity).
__global__ __launch_bounds__(256) void gap_k3(const float* __restrict__ fin,
                                              float* __restrict__ out, int n) {
  __shared__ float s_fin[20];
  if (threadIdx.x < 20) s_fin[threadIdx.x] = fin[threadIdx.x];
  __syncthreads();
  float mk[10], rsk[10];
#pragma unroll
  for (int k = 0; k < 10; ++k) {
    mk[k] = s_fin[2 * k];
    rsk[k] = 1.0f / s_fin[2 * k + 1];
  }
  float* out0 = out;
  const float* out1 = out + (size_t)n * 16;
  const int q = threadIdx.x & 3;
  const int pl = threadIdx.x >> 2;           // 64 points per block pass
  for (long i = (long)blockIdx.x * 64 + pl; i < n; i += (long)gridDim.x * 64) {
    float* lrow = out0 + i * 16;
    // all 4 lanes of the quad read the same 64B logit line (L1 broadcast)
    float4 la = *(const float4*)(lrow);
    float4 lb = *(const float4*)(lrow + 4);
    float2 lc = *(const float2*)(lrow + 8);
    float l[10] = {la.x, la.y, la.z, la.w, lb.x, lb.y, lb.z, lb.w, lc.x, lc.y};
    float w[10];
#pragma unroll
    for (int k = 0; k < 10; ++k) w[k] = __expf(l[k] - mk[k]) * rsk[k];
    const float* vrow = out1 + i * 160 + q * 4;
    float4 acc = make_float4(0.f, 0.f, 0.f, 0.f);
#pragma unroll
    for (int k = 0; k < 10; ++k) {
      float4 v = *(const float4*)(vrow + k * 16);
      float wk = w[k];
      acc.x = fmaf(wk, v.x, acc.x);
      acc.y = fmaf(wk, v.y, acc.y);
      acc.z = fmaf(wk, v.z, acc.z);
      acc.w = fmaf(wk, v.w, acc.w);
    }
    // store after all reads (wave-lockstep => no RAW hazard on the logit line)
    *(float4*)(lrow + q * 4) = acc;
  }
}

extern "C" void kernel_launch(void* const* d_in, const int* in_sizes, int n_in,
                              void* d_out, int out_size, void* d_ws, size_t ws_size,
                              hipStream_t stream) {
  const float* xknn = (const float*)d_in[0];
  const float* x    = (const float*)d_in[1];
  const float* Wf   = (const float*)d_in[2];
  const float* bf   = (const float*)d_in[3];
  const float* W1   = (const float*)d_in[4];
  const float* b1   = (const float*)d_in[5];
  float* out = (float*)d_out;
  const int n = in_sizes[1] / 16;  // x is [N][16]

  const int G1 = 1024;
  float* partials = (float*)d_ws;                 // [G1][10][2]
  float* finals = partials + (size_t)G1 * 20;     // [10][2]

  gap_k1<<<G1, 256, 0, stream>>>(xknn, x, Wf, bf, W1, b1, out, partials, n);
  gap_k2<<<10, 256, 0, stream>>>(partials, G1, finals);
  gap_k3<<<2048, 256, 0, stream>>>(finals, out, n);
}

// Round 11
// 589.798 us; speedup vs baseline: 2.8820x; 1.5689x over previous
//
#include <hip/hip_runtime.h>
#include <math.h>

// SingleGAP: per-point tiny MLPs + GLOBAL softmax over N (axis 0, faithful bug),
// then attention-weighted sum. out0 = [N][16] x_attn, out1 = [N][160] h2 (flat,
// [F][K] order per point == x2v raw reshape).
//
// K1 (octet, R8 structure, NO forced launch bounds): 8 lanes/point, lane o owns
//     f={2o,2o+1}. Loads sector-major (own[i] = row[32i+4o..+3] -> 128B/point
//     per instr). Cross-lane x2 distribution via ds_swizzle 8-lane broadcast.
//     Natural VGPR demand ~100 -> 4 waves/SIMD without spill (the R6/R8/R9/R10
//     regressions were all launch_bounds-forced scratch spill: +0.6-2.3GB HBM).
//     Stores: logits float2 (full 64B/point across octet), h2 quarters at 80B
//     stride (R2-proven clean on this L2 -- partial-line stores merge, no RFO).
// K2: reduce per-block (m,s) -> global (m,s) per k-slot.
// K3: quad-per-point weighted sum: out0 = softmax(logits) @ x2v.

__device__ __forceinline__ void comb(float& m, float& s, float om, float os) {
  float M = fmaxf(m, om);
  if (M == -INFINITY) return;  // both empty
  s = s * __expf(m - M) + os * __expf(om - M);
  m = M;
}

// Broadcast lane (group_base + B) to all 8 lanes of its group (groups of 8).
// ds_swizzle BitMode: src_lane = (lane & 0x18) | B  (per 32-lane half).
template <int B>
__device__ __forceinline__ float swz8(float v) {
  return __int_as_float(
      __builtin_amdgcn_ds_swizzle(__float_as_int(v), (B << 5) | 0x18));
}

__device__ __forceinline__ float f4e(const float4& v, int e) {
  return (e == 0) ? v.x : (e == 1) ? v.y : (e == 2) ? v.z : v.w;
}

__global__ __launch_bounds__(256) void gap_k1(
    const float* __restrict__ xknn, const float* __restrict__ x,
    const float* __restrict__ Wf, const float* __restrict__ bf,
    const float* __restrict__ W1, const float* __restrict__ b1p,
    float* __restrict__ out, float* __restrict__ partials, int n) {
  __shared__ float s_red[4][16][2];

  const int tid = threadIdx.x;
  const int o = tid & 7;        // octet lane: owns f = {2o,2o+1}
  const int p8 = tid >> 3;      // point-in-block 0..31
  const int lane = tid & 63;
  const int wave = tid >> 6;

  // per-lane weights: Wf rows {2o,2o+1}
  float wfo[2][16], w1o[2], bfo[2];
#pragma unroll
  for (int fp = 0; fp < 2; ++fp) {
    const float* wr = Wf + (size_t)(2 * o + fp) * 16;
#pragma unroll
    for (int dq = 0; dq < 4; ++dq) {
      float4 v = *(const float4*)(wr + dq * 4);
      wfo[fp][dq * 4 + 0] = v.x;
      wfo[fp][dq * 4 + 1] = v.y;
      wfo[fp][dq * 4 + 2] = v.z;
      wfo[fp][dq * 4 + 3] = v.w;
    }
    w1o[fp] = W1[2 * o + fp];
    bfo[fp] = bf[2 * o + fp];
  }
  const float b1v = b1p[0];

  // u[d] = sum_f W1[f] Wf[f][d]; keep only own pair u2 = {u[2o], u[2o+1]}
  float u2[2];
  {
    float ufull[16];
#pragma unroll
    for (int d = 0; d < 16; ++d)
      ufull[d] = fmaf(w1o[1], wfo[1][d], w1o[0] * wfo[0][d]);
#pragma unroll
    for (int mk = 1; mk < 8; mk <<= 1)
#pragma unroll
      for (int d = 0; d < 16; ++d) ufull[d] += __shfl_xor(ufull[d], mk);
#pragma unroll
    for (int j = 0; j < 2; ++j) {
      float v = ufull[j];
#pragma unroll
      for (int oo = 1; oo < 8; ++oo) v = (o == oo) ? ufull[2 * oo + j] : v;
      u2[j] = v;
    }
  }
  float sb = fmaf(w1o[1], bfo[1], w1o[0] * bfo[0]);
  sb += __shfl_xor(sb, 1);
  sb += __shfl_xor(sb, 2);
  sb += __shfl_xor(sb, 4);
  const float addA = sb + 2.0f * b1v;  // logit = t[k] + a1u + addA

  // online softmax state for owned k = {2o,2o+1} (valid for o<5)
  float rm[2] = {-INFINITY, -INFINITY}, rs[2] = {0.f, 0.f};

  float* out0 = out;                       // [n][16]  (logits now, x_attn later)
  float* out1 = out + (size_t)n * 16;      // [n][160] h2 flat ([F][K] per point)

  const long pt0 = (long)blockIdx.x * 32 + p8;
  const long pstride = (long)gridDim.x * 32;

  for (long pt = pt0; pt < n; pt += pstride) {
    // sector-major loads: instr i covers row bytes [128i,128i+128) per point
    const float* row = xknn + (size_t)pt * 160;
    float4 own[5];
#pragma unroll
    for (int i = 0; i < 5; ++i)
      own[i] = *(const float4*)(row + 32 * i + 4 * o);
    const float2 xc = *(const float2*)(x + (size_t)pt * 16 + 2 * o);

    // acc[fp][k] = bf + sum_d Wf[fp][d] x2[d][k]; element r = 32i + 4*src + e
    float acc0[10], acc1[10];
#pragma unroll
    for (int k = 0; k < 10; ++k) {
      acc0[k] = bfo[0];
      acc1[k] = bfo[1];
    }
#pragma unroll
    for (int i = 0; i < 5; ++i) {
#pragma unroll
      for (int e = 0; e < 4; ++e) {
        const float mine = f4e(own[i], e);
        {
          const int r = 32 * i + 0 + e, d = r / 10, k = r % 10;
          const float xv = swz8<0>(mine);
          acc0[k] = fmaf(wfo[0][d], xv, acc0[k]);
          acc1[k] = fmaf(wfo[1][d], xv, acc1[k]);
        }
        {
          const int r = 32 * i + 4 + e, d = r / 10, k = r % 10;
          const float xv = swz8<1>(mine);
          acc0[k] = fmaf(wfo[0][d], xv, acc0[k]);
          acc1[k] = fmaf(wfo[1][d], xv, acc1[k]);
        }
        {
          const int r = 32 * i + 8 + e, d = r / 10, k = r % 10;
          const float xv = swz8<2>(mine);
          acc0[k] = fmaf(wfo[0][d], xv, acc0[k]);
          acc1[k] = fmaf(wfo[1][d], xv, acc1[k]);
        }
        {
          const int r = 32 * i + 12 + e, d = r / 10, k = r % 10;
          const float xv = swz8<3>(mine);
          acc0[k] = fmaf(wfo[0][d], xv, acc0[k]);
          acc1[k] = fmaf(wfo[1][d], xv, acc1[k]);
        }
        {
          const int r = 32 * i + 16 + e, d = r / 10, k = r % 10;
          const float xv = swz8<4>(mine);
          acc0[k] = fmaf(wfo[0][d], xv, acc0[k]);
          acc1[k] = fmaf(wfo[1][d], xv, acc1[k]);
        }
        {
          const int r = 32 * i + 20 + e, d = r / 10, k = r % 10;
          const float xv = swz8<5>(mine);
          acc0[k] = fmaf(wfo[0][d], xv, acc0[k]);
          acc1[k] = fmaf(wfo[1][d], xv, acc1[k]);
        }
        {
          const int r = 32 * i + 24 + e, d = r / 10, k = r % 10;
          const float xv = swz8<6>(mine);
          acc0[k] = fmaf(wfo[0][d], xv, acc0[k]);
          acc1[k] = fmaf(wfo[1][d], xv, acc1[k]);
        }
        {
          const int r = 32 * i + 28 + e, d = r / 10, k = r % 10;
          const float xv = swz8<7>(mine);
          acc0[k] = fmaf(wfo[0][d], xv, acc0[k]);
          acc1[k] = fmaf(wfo[1][d], xv, acc1[k]);
        }
      }
    }

    // a2[k]+sb via 3-step octet butterfly
    float tk[10];
#pragma unroll
    for (int k = 0; k < 10; ++k)
      tk[k] = fmaf(w1o[1], acc1[k], w1o[0] * acc0[k]);
#pragma unroll
    for (int k = 0; k < 10; ++k) tk[k] += __shfl_xor(tk[k], 1);
#pragma unroll
    for (int k = 0; k < 10; ++k) tk[k] += __shfl_xor(tk[k], 2);
#pragma unroll
    for (int k = 0; k < 10; ++k) tk[k] += __shfl_xor(tk[k], 4);

    // a1u = sum_d u[d] x[d] (octet butterfly)
    float a1u = fmaf(u2[1], xc.y, u2[0] * xc.x);
    a1u += __shfl_xor(a1u, 1);
    a1u += __shfl_xor(a1u, 2);
    a1u += __shfl_xor(a1u, 4);
    const float addc = a1u + addA;

    // logits k = {2o, 2o+1} (cndmask chains; no runtime array index)
    float lj0 = 0.f, lj1 = 0.f;
#pragma unroll
    for (int kk = 0; kk < 10; ++kk) {
      lj0 = (kk == 2 * o) ? (tk[kk] + addc) : lj0;
      lj1 = (kk == 2 * o + 1) ? (tk[kk] + addc) : lj1;
    }

    *(float2*)(out0 + (size_t)pt * 16 + 2 * o) = make_float2(lj0, lj1);
    if (o < 5) {
      comb(rm[0], rs[0], lj0, 1.0f);
      comb(rm[1], rs[1], lj1, 1.0f);
    }
    // h2 -> out1 flat [F][K]: lane o's region [20o, 20o+20), 80B contiguous
    // (partial-line store class measured clean in R2: L2 merges, no RFO)
    float* o1 = out1 + (size_t)pt * 160 + 20 * o;
    *(float4*)(o1 + 0) = make_float4(acc0[0], acc0[1], acc0[2], acc0[3]);
    *(float4*)(o1 + 4) = make_float4(acc0[4], acc0[5], acc0[6], acc0[7]);
    *(float4*)(o1 + 8) = make_float4(acc0[8], acc0[9], acc1[0], acc1[1]);
    *(float4*)(o1 + 12) = make_float4(acc1[2], acc1[3], acc1[4], acc1[5]);
    *(float4*)(o1 + 16) = make_float4(acc1[6], acc1[7], acc1[8], acc1[9]);
  }

  // (m,s) reduce across the wave's 8 points (lane bits 3..5), then block
#pragma unroll
  for (int mk = 8; mk < 64; mk <<= 1) {
#pragma unroll
    for (int j = 0; j < 2; ++j) {
      float om = __shfl_xor(rm[j], mk);
      float os = __shfl_xor(rs[j], mk);
      comb(rm[j], rs[j], om, os);
    }
  }
  if (lane < 5) {
#pragma unroll
    for (int j = 0; j < 2; ++j) {
      s_red[wave][2 * lane + j][0] = rm[j];
      s_red[wave][2 * lane + j][1] = rs[j];
    }
  }
  __syncthreads();
  if (tid < 10) {
    float m = s_red[0][tid][0], s = s_red[0][tid][1];
    comb(m, s, s_red[1][tid][0], s_red[1][tid][1]);
    comb(m, s, s_red[2][tid][0], s_red[2][tid][1]);
    comb(m, s, s_red[3][tid][0], s_red[3][tid][1]);
    partials[(size_t)blockIdx.x * 20 + tid * 2 + 0] = m;
    partials[(size_t)blockIdx.x * 20 + tid * 2 + 1] = s;
  }
}

__global__ __launch_bounds__(256) void gap_k2(const float* __restrict__ part,
                                              int nb, float* __restrict__ fin) {
  const int k = blockIdx.x;   // one block per k-slot
  const int tid = threadIdx.x;
  float m = -INFINITY, s = 0.f;
  for (int i = tid; i < nb; i += 256)
    comb(m, s, part[(size_t)i * 20 + k * 2], part[(size_t)i * 20 + k * 2 + 1]);
#pragma unroll
  for (int mask = 1; mask < 64; mask <<= 1) {
    float om = __shfl_xor(m, mask, 64);
    float os = __shfl_xor(s, mask, 64);
    comb(m, s, om, os);
  }
  __shared__ float sm[4][2];
  const int wave = tid >> 6, lane = tid & 63;
  if (lane == 0) { sm[wave][0] = m; sm[wave][1] = s; }
  __syncthreads();
  if (tid == 0) {
    for (int w = 1; w < 4; ++w) comb(m, s, sm[w][0], sm[w][1]);
    fin[k * 2 + 0] = m;
    fin[k * 2 + 1] = s;
  }
}

// K3: 4 lanes per point; lane (p,q) accumulates features f = 4q..4q+3.
// Reads out1 flat at offset k*16+f == x2v[k][f] (raw-reshape identity).
__global__ __launch_bounds__(256) void gap_k3(const float* __restrict__ fin,
                                              float* __restrict__ out, int n) {
  __shared__ float s_fin[20];
  if (threadIdx.x < 20) s_fin[threadIdx.x] = fin[threadIdx.x];
  __syncthreads();
  float mk[10], rsk[10];
#pragma unroll
  for (int k = 0; k < 10; ++k) {
    mk[k] = s_fin[2 * k];
    rsk[k] = 1.0f / s_fin[2 * k + 1];
  }
  float* out0 = out;
  const float* out1 = out + (size_t)n * 16;
  const int q = threadIdx.x & 3;
  const int pl = threadIdx.x >> 2;           // 64 points per block pass
  for (long i = (long)blockIdx.x * 64 + pl; i < n; i += (long)gridDim.x * 64) {
    float* lrow = out0 + i * 16;
    // all 4 lanes of the quad read the same 64B logit line (L1 broadcast)
    float4 la = *(const float4*)(lrow);
    float4 lb = *(const float4*)(lrow + 4);
    float2 lc = *(const float2*)(lrow + 8);
    float l[10] = {la.x, la.y, la.z, la.w, lb.x, lb.y, lb.z, lb.w, lc.x, lc.y};
    float w[10];
#pragma unroll
    for (int k = 0; k < 10; ++k) w[k] = __expf(l[k] - mk[k]) * rsk[k];
    const float* vrow = out1 + i * 160 + q * 4;
    float4 acc = make_float4(0.f, 0.f, 0.f, 0.f);
#pragma unroll
    for (int k = 0; k < 10; ++k) {
      float4 v = *(const float4*)(vrow + k * 16);
      float wk = w[k];
      acc.x = fmaf(wk, v.x, acc.x);
      acc.y = fmaf(wk, v.y, acc.y);
      acc.z = fmaf(wk, v.z, acc.z);
      acc.w = fmaf(wk, v.w, acc.w);
    }
    // store after all reads (wave-lockstep => no RAW hazard on the logit line)
    *(float4*)(lrow + q * 4) = acc;
  }
}

extern "C" void kernel_launch(void* const* d_in, const int* in_sizes, int n_in,
                              void* d_out, int out_size, void* d_ws, size_t ws_size,
                              hipStream_t stream) {
  const float* xknn = (const float*)d_in[0];
  const float* x    = (const float*)d_in[1];
  const float* Wf   = (const float*)d_in[2];
  const float* bf   = (const float*)d_in[3];
  const float* W1   = (const float*)d_in[4];
  const float* b1   = (const float*)d_in[5];
  float* out = (float*)d_out;
  const int n = in_sizes[1] / 16;  // x is [N][16]

  const int G1 = 2048;
  float* partials = (float*)d_ws;                 // [G1][10][2]
  float* finals = partials + (size_t)G1 * 20;     // [10][2]

  gap_k1<<<G1, 256, 0, stream>>>(xknn, x, Wf, bf, W1, b1, out, partials, n);
  gap_k2<<<10, 256, 0, stream>>>(partials, G1, finals);
  gap_k3<<<2048, 256, 0, stream>>>(finals, out, n);
}

// Round 12
// 559.734 us; speedup vs baseline: 3.0368x; 1.0537x over previous
//
#include <hip/hip_runtime.h>
#include <math.h>

// SingleGAP: per-point tiny MLPs + GLOBAL softmax over N (axis 0, faithful bug),
// then attention-weighted sum. out0 = [N][16] x_attn, out1 = [N][160] h2 (flat,
// [F][K] order per point == x2v raw reshape).
//
// K1 (octet = 2 mirrored quads, ALL cross-lane via DPP -> zero DS in hot loop):
//     8 lanes/point, lane o owns f={2o,2o+1} and loads chunk o&3 (elements
//     [40(o&3),40(o&3)+40)) -- lanes o and o+4 duplicate loads (L1 dedups, the
//     R4 counter-proof: FETCH stays 344MB). Full row lives in EACH quad ->
//     x2 broadcasts are quad_perm DPP; f-reductions are xor1/xor2 DPP +
//     ROW_HALF_MIRROR DPP (cross-quad). No launch_bounds coercion (R6/8/9/10
//     lesson: forced bounds => scratch spill => +0.6-2.3GB HBM).
// K2: reduce per-block (m,s) -> global (m,s) per k-slot.
// K3: quad-per-point weighted sum: out0 = softmax(logits) @ x2v.

__device__ __forceinline__ void comb(float& m, float& s, float om, float os) {
  float M = fmaxf(m, om);
  if (M == -INFINITY) return;  // both empty
  s = s * __expf(m - M) + os * __expf(om - M);
  m = M;
}

// Generic DPP move: result[lane] = v[ctrl-mapped lane]. VALU op, no DS pipe.
template <int CTRL>
__device__ __forceinline__ float dppmov(float v) {
  return __int_as_float(__builtin_amdgcn_update_dpp(
      0, __float_as_int(v), CTRL, 0xf, 0xf, true));
}

// Octet butterfly sum, all-DPP: xor1 (quad_perm [1,0,3,2]=0xB1),
// xor2 (quad_perm [2,3,0,1]=0x4E), cross-quad (ROW_HALF_MIRROR=0x141).
__device__ __forceinline__ float osum(float v) {
  v += dppmov<0xB1>(v);
  v += dppmov<0x4E>(v);
  v += dppmov<0x141>(v);
  return v;
}

__device__ __forceinline__ float f4e(const float4& v, int e) {
  return (e == 0) ? v.x : (e == 1) ? v.y : (e == 2) ? v.z : v.w;
}

__global__ __launch_bounds__(256) void gap_k1(
    const float* __restrict__ xknn, const float* __restrict__ x,
    const float* __restrict__ Wf, const float* __restrict__ bf,
    const float* __restrict__ W1, const float* __restrict__ b1p,
    float* __restrict__ out, float* __restrict__ partials, int n) {
  __shared__ float s_red[4][16][2];

  const int tid = threadIdx.x;
  const int o = tid & 7;        // octet lane: owns f = {2o,2o+1}, chunk o&3
  const int c = o & 3;          // data chunk (duplicated across the 2 quads)
  const int p8 = tid >> 3;      // point-in-block 0..31
  const int lane = tid & 63;
  const int wave = tid >> 6;

  // per-lane weights: Wf rows {2o,2o+1}
  float wfo[2][16], w1o[2], bfo[2];
#pragma unroll
  for (int fp = 0; fp < 2; ++fp) {
    const float* wr = Wf + (size_t)(2 * o + fp) * 16;
#pragma unroll
    for (int dq = 0; dq < 4; ++dq) {
      float4 v = *(const float4*)(wr + dq * 4);
      wfo[fp][dq * 4 + 0] = v.x;
      wfo[fp][dq * 4 + 1] = v.y;
      wfo[fp][dq * 4 + 2] = v.z;
      wfo[fp][dq * 4 + 3] = v.w;
    }
    w1o[fp] = W1[2 * o + fp];
    bfo[fp] = bf[2 * o + fp];
  }
  const float b1v = b1p[0];

  // u[d] = sum_f W1[f] Wf[f][d]; keep only own pair u2 = {u[2o], u[2o+1]}
  // (prologue-only; __shfl_xor here may use DS -- cold path, fine)
  float u2[2];
  {
    float ufull[16];
#pragma unroll
    for (int d = 0; d < 16; ++d)
      ufull[d] = fmaf(w1o[1], wfo[1][d], w1o[0] * wfo[0][d]);
#pragma unroll
    for (int mk = 1; mk < 8; mk <<= 1)
#pragma unroll
      for (int d = 0; d < 16; ++d) ufull[d] += __shfl_xor(ufull[d], mk);
#pragma unroll
    for (int j = 0; j < 2; ++j) {
      float v = ufull[j];
#pragma unroll
      for (int oo = 1; oo < 8; ++oo) v = (o == oo) ? ufull[2 * oo + j] : v;
      u2[j] = v;
    }
  }
  float sb = fmaf(w1o[1], bfo[1], w1o[0] * bfo[0]);
  sb += __shfl_xor(sb, 1);
  sb += __shfl_xor(sb, 2);
  sb += __shfl_xor(sb, 4);
  const float addA = sb + 2.0f * b1v;  // logit = tk[k] + a1u + addA

  // online softmax state for owned k = {2o,2o+1} (valid for o<5)
  float rm[2] = {-INFINITY, -INFINITY}, rs[2] = {0.f, 0.f};

  float* out0 = out;                       // [n][16]  (logits now, x_attn later)
  float* out1 = out + (size_t)n * 16;      // [n][160] h2 flat ([F][K] per point)

  const long pt0 = (long)blockIdx.x * 32 + p8;
  const long pstride = (long)gridDim.x * 32;

  for (long pt = pt0; pt < n; pt += pstride) {
    // own chunk: contiguous 160B [40c,40c+40); lanes o and o+4 duplicate ->
    // wave issues 10 loads covering all 8 points' rows (L1 dedups the 2x).
    const float* rowq = xknn + (size_t)pt * 160 + 40 * c;
    float4 own[10];
#pragma unroll
    for (int j = 0; j < 10; ++j) own[j] = *(const float4*)(rowq + 4 * j);
    const float2 xc = *(const float2*)(x + (size_t)pt * 16 + 2 * o);

    // acc[fp][k] = bf + sum_d Wf[fp][d] x2[d][k]; element r = 40*src + rr,
    // broadcast from quad-lane src via quad_perm DPP (VALU, no DS).
    float acc0[10], acc1[10];
#pragma unroll
    for (int k = 0; k < 10; ++k) {
      acc0[k] = bfo[0];
      acc1[k] = bfo[1];
    }
#pragma unroll
    for (int src = 0; src < 4; ++src) {
#pragma unroll
      for (int rr = 0; rr < 40; ++rr) {
        const int r = 40 * src + rr;
        const int d = r / 10, k = r - d * 10;
        const float mine = f4e(own[rr >> 2], rr & 3);
        const float xv = (src == 0)   ? dppmov<0x00>(mine)
                         : (src == 1) ? dppmov<0x55>(mine)
                         : (src == 2) ? dppmov<0xAA>(mine)
                                      : dppmov<0xFF>(mine);
        acc0[k] = fmaf(wfo[0][d], xv, acc0[k]);
        acc1[k] = fmaf(wfo[1][d], xv, acc1[k]);
      }
    }

    // h2 -> out1 flat [F][K]: lane o's region [20o,20o+20); octet covers the
    // full 640B row contiguously (R2-proven clean store class).
    float* o1 = out1 + (size_t)pt * 160 + 20 * o;
    *(float4*)(o1 + 0) = make_float4(acc0[0], acc0[1], acc0[2], acc0[3]);
    *(float4*)(o1 + 4) = make_float4(acc0[4], acc0[5], acc0[6], acc0[7]);
    *(float4*)(o1 + 8) = make_float4(acc0[8], acc0[9], acc1[0], acc1[1]);
    *(float4*)(o1 + 12) = make_float4(acc1[2], acc1[3], acc1[4], acc1[5]);
    *(float4*)(o1 + 16) = make_float4(acc1[6], acc1[7], acc1[8], acc1[9]);

    // tk[k] = sum_f W1[f] h2[f][k] via all-DPP octet butterfly
    float tk[10];
#pragma unroll
    for (int k = 0; k < 10; ++k)
      tk[k] = osum(fmaf(w1o[1], acc1[k], w1o[0] * acc0[k]));

    // a1u = sum_d u[d] x[d] via all-DPP octet butterfly
    const float a1u = osum(fmaf(u2[1], xc.y, u2[0] * xc.x));
    const float addc = a1u + addA;

    // logits k = {2o, 2o+1} (cndmask chains; no runtime array index)
    float lj0 = 0.f, lj1 = 0.f;
#pragma unroll
    for (int kk = 0; kk < 10; ++kk) {
      lj0 = (kk == 2 * o) ? (tk[kk] + addc) : lj0;
      lj1 = (kk == 2 * o + 1) ? (tk[kk] + addc) : lj1;
    }

    *(float2*)(out0 + (size_t)pt * 16 + 2 * o) = make_float2(lj0, lj1);
    if (o < 5) {
      comb(rm[0], rs[0], lj0, 1.0f);
      comb(rm[1], rs[1], lj1, 1.0f);
    }
  }

  // (m,s) reduce across the wave's 8 points (lane bits 3..5), then block
  // (epilogue-only; __shfl_xor DS cost irrelevant here)
#pragma unroll
  for (int mk = 8; mk < 64; mk <<= 1) {
#pragma unroll
    for (int j = 0; j < 2; ++j) {
      float om = __shfl_xor(rm[j], mk);
      float os = __shfl_xor(rs[j], mk);
      comb(rm[j], rs[j], om, os);
    }
  }
  if (lane < 5) {
#pragma unroll
    for (int j = 0; j < 2; ++j) {
      s_red[wave][2 * lane + j][0] = rm[j];
      s_red[wave][2 * lane + j][1] = rs[j];
    }
  }
  __syncthreads();
  if (tid < 10) {
    float m = s_red[0][tid][0], s = s_red[0][tid][1];
    comb(m, s, s_red[1][tid][0], s_red[1][tid][1]);
    comb(m, s, s_red[2][tid][0], s_red[2][tid][1]);
    comb(m, s, s_red[3][tid][0], s_red[3][tid][1]);
    partials[(size_t)blockIdx.x * 20 + tid * 2 + 0] = m;
    partials[(size_t)blockIdx.x * 20 + tid * 2 + 1] = s;
  }
}

__global__ __launch_bounds__(256) void gap_k2(const float* __restrict__ part,
                                              int nb, float* __restrict__ fin) {
  const int k = blockIdx.x;   // one block per k-slot
  const int tid = threadIdx.x;
  float m = -INFINITY, s = 0.f;
  for (int i = tid; i < nb; i += 256)
    comb(m, s, part[(size_t)i * 20 + k * 2], part[(size_t)i * 20 + k * 2 + 1]);
#pragma unroll
  for (int mask = 1; mask < 64; mask <<= 1) {
    float om = __shfl_xor(m, mask, 64);
    float os = __shfl_xor(s, mask, 64);
    comb(m, s, om, os);
  }
  __shared__ float sm[4][2];
  const int wave = tid >> 6, lane = tid & 63;
  if (lane == 0) { sm[wave][0] = m; sm[wave][1] = s; }
  __syncthreads();
  if (tid == 0) {
    for (int w = 1; w < 4; ++w) comb(m, s, sm[w][0], sm[w][1]);
    fin[k * 2 + 0] = m;
    fin[k * 2 + 1] = s;
  }
}

// K3: 4 lanes per point; lane (p,q) accumulates features f = 4q..4q+3.
// Reads out1 flat at offset k*16+f == x2v[k][f] (raw-reshape identity).
__global__ __launch_bounds__(256) void gap_k3(const float* __restrict__ fin,
                                              float* __restrict__ out, int n) {
  __shared__ float s_fin[20];
  if (threadIdx.x < 20) s_fin[threadIdx.x] = fin[threadIdx.x];
  __syncthreads();
  float mk[10], rsk[10];
#pragma unroll
  for (int k = 0; k < 10; ++k) {
    mk[k] = s_fin[2 * k];
    rsk[k] = 1.0f / s_fin[2 * k + 1];
  }
  float* out0 = out;
  const float* out1 = out + (size_t)n * 16;
  const int q = threadIdx.x & 3;
  const int pl = threadIdx.x >> 2;           // 64 points per block pass
  for (long i = (long)blockIdx.x * 64 + pl; i < n; i += (long)gridDim.x * 64) {
    float* lrow = out0 + i * 16;
    // all 4 lanes of the quad read the same 64B logit line (L1 broadcast)
    float4 la = *(const float4*)(lrow);
    float4 lb = *(const float4*)(lrow + 4);
    float2 lc = *(const float2*)(lrow + 8);
    float l[10] = {la.x, la.y, la.z, la.w, lb.x, lb.y, lb.z, lb.w, lc.x, lc.y};
    float w[10];
#pragma unroll
    for (int k = 0; k < 10; ++k) w[k] = __expf(l[k] - mk[k]) * rsk[k];
    const float* vrow = out1 + i * 160 + q * 4;
    float4 acc = make_float4(0.f, 0.f, 0.f, 0.f);
#pragma unroll
    for (int k = 0; k < 10; ++k) {
      float4 v = *(const float4*)(vrow + k * 16);
      float wk = w[k];
      acc.x = fmaf(wk, v.x, acc.x);
      acc.y = fmaf(wk, v.y, acc.y);
      acc.z = fmaf(wk, v.z, acc.z);
      acc.w = fmaf(wk, v.w, acc.w);
    }
    // store after all reads (wave-lockstep => no RAW hazard on the logit line)
    *(float4*)(lrow + q * 4) = acc;
  }
}

extern "C" void kernel_launch(void* const* d_in, const int* in_sizes, int n_in,
                              void* d_out, int out_size, void* d_ws, size_t ws_size,
                              hipStream_t stream) {
  const float* xknn = (const float*)d_in[0];
  const float* x    = (const float*)d_in[1];
  const float* Wf   = (const float*)d_in[2];
  const float* bf   = (const float*)d_in[3];
  const float* W1   = (const float*)d_in[4];
  const float* b1   = (const float*)d_in[5];
  float* out = (float*)d_out;
  const int n = in_sizes[1] / 16;  // x is [N][16]

  const int G1 = 2048;
  float* partials = (float*)d_ws;                 // [G1][10][2]
  float* finals = partials + (size_t)G1 * 20;     // [10][2]

  gap_k1<<<G1, 256, 0, stream>>>(xknn, x, Wf, bf, W1, b1, out, partials, n);
  gap_k2<<<10, 256, 0, stream>>>(partials, G1, finals);
  gap_k3<<<2048, 256, 0, stream>>>(finals, out, n);
}